// Round 1
// baseline (180.624 us; speedup 1.0000x reference)
//
#include <hip/hip_runtime.h>
#include <hip/hip_bf16.h>

#define B_ROWS 131072
#define H 128
#define BM 32

typedef __bf16 bf16x8 __attribute__((ext_vector_type(8)));
typedef float f32x4 __attribute__((ext_vector_type(4)));

struct WPtrs {
    const float* wx[4];
    const float* wh[4];
    const float* bx[4];
    const float* bh[4];
};

// Build Wcat[n][k]: n in [0,512) = gate*128 + hidden_row; k in [0,256) = [X-k | h-k].
// Also bsum[n] = bx + bh.
__global__ __launch_bounds__(256) void prep_weights(WPtrs p, __bf16* __restrict__ wcat,
                                                    float* __restrict__ bsum) {
    int n = blockIdx.x;      // 0..511
    int k = threadIdx.x;     // 0..255
    int g = n >> 7, r = n & 127;
    float v = (k < H) ? p.wx[g][r * H + k] : p.wh[g][r * H + (k - H)];
    wcat[n * 256 + k] = (__bf16)v;
    if (k == 0) bsum[n] = p.bx[g][r] + p.bh[g][r];
}

__global__ __launch_bounds__(256) void lstm_fused(
    const float* __restrict__ X, const float* __restrict__ Hp, const float* __restrict__ Cp,
    const __bf16* __restrict__ Wcat, const float* __restrict__ Bsum,
    float* __restrict__ out)
{
    // 32 rows x 256 bf16 (512 B/row), XOR-swizzled to kill the 512B-stride bank conflict
    __shared__ char lds[BM * 512];
    const int t = threadIdx.x;
    const int lane = t & 63;
    const int wv = t >> 6;                 // wave 0..3 -> hidden cols [wv*32, wv*32+32)
    const long r0 = (long)blockIdx.x * BM;

    // ---- stage X|Hp tile to LDS as bf16 (coalesced float4 reads) ----
#pragma unroll
    for (int i = 0; i < 4; ++i) {
        int fi = i * 256 + t;              // 0..1023
        int row = fi >> 5;                 // 32 float4 per 128-col row
        int kv = fi & 31;
        float4 vx = *(const float4*)(X + (r0 + row) * H + kv * 4);
        float4 vh = *(const float4*)(Hp + (r0 + row) * H + kv * 4);
        union { __bf16 b[4]; unsigned long long u; } px, ph;
        px.b[0] = (__bf16)vx.x; px.b[1] = (__bf16)vx.y;
        px.b[2] = (__bf16)vx.z; px.b[3] = (__bf16)vx.w;
        ph.b[0] = (__bf16)vh.x; ph.b[1] = (__bf16)vh.y;
        ph.b[2] = (__bf16)vh.z; ph.b[3] = (__bf16)vh.w;
        int swz = (row & 7) << 4;
        *(unsigned long long*)(lds + row * 512 + ((kv * 8) ^ swz)) = px.u;
        *(unsigned long long*)(lds + row * 512 + ((256 + kv * 8) ^ swz)) = ph.u;
    }
    __syncthreads();

    const int l16 = lane & 15;
    const int kg = lane >> 4;

    f32x4 acc[4][2][2] = {};   // [gate][col-subtile][row-tile]

    // W fragment base: n = g*128 + wv*32 + tt*16 + l16; elem = n*256 + kg*8 (+ kc*32)
    const __bf16* wbase = Wcat + (wv * 32 + l16) * 256 + kg * 8;

#pragma unroll
    for (int kc = 0; kc < 8; ++kc) {
        bf16x8 a[2];
#pragma unroll
        for (int rt = 0; rt < 2; ++rt) {
            int row = rt * 16 + l16;
            int off = row * 512 + ((kc * 64 + kg * 16) ^ ((row & 7) << 4));
            a[rt] = *(const bf16x8*)(lds + off);
        }
#pragma unroll
        for (int g = 0; g < 4; ++g) {
#pragma unroll
            for (int tt = 0; tt < 2; ++tt) {
                bf16x8 b = *(const bf16x8*)(wbase + g * 32768 + tt * 4096 + kc * 32);
                acc[g][tt][0] = __builtin_amdgcn_mfma_f32_16x16x32_bf16(a[0], b, acc[g][tt][0], 0, 0, 0);
                acc[g][tt][1] = __builtin_amdgcn_mfma_f32_16x16x32_bf16(a[1], b, acc[g][tt][1], 0, 0, 0);
            }
        }
    }

    // ---- epilogue: bias + activations, all 4 gates lane-local ----
    float bias[4][2];
#pragma unroll
    for (int g = 0; g < 4; ++g)
#pragma unroll
        for (int tt = 0; tt < 2; ++tt)
            bias[g][tt] = Bsum[g * H + wv * 32 + tt * 16 + l16];

    const long c_off = (long)B_ROWS * H;
#pragma unroll
    for (int tt = 0; tt < 2; ++tt) {
        int j = wv * 32 + tt * 16 + l16;
#pragma unroll
        for (int rt = 0; rt < 2; ++rt) {
#pragma unroll
            for (int r = 0; r < 4; ++r) {
                long row = r0 + rt * 16 + kg * 4 + r;   // C/D layout: row=(lane>>4)*4+reg
                float f  = acc[0][tt][rt][r] + bias[0][tt];
                float ii = acc[1][tt][rt][r] + bias[1][tt];
                float cl = acc[2][tt][rt][r] + bias[2][tt];
                float oo = acc[3][tt][rt][r] + bias[3][tt];
                float cp = Cp[row * H + j];
                float ft = 1.0f / (1.0f + __expf(-f));
                float it = 1.0f / (1.0f + __expf(-ii));
                float cc = 1.0f - 2.0f / (__expf(2.0f * cl) + 1.0f);
                float ot = 1.0f / (1.0f + __expf(-oo));
                float ct = ft * cp + it * cc;
                float th = 1.0f - 2.0f / (__expf(2.0f * ct) + 1.0f);
                out[row * H + j] = ot * th;
                out[c_off + row * H + j] = ct;
            }
        }
    }
}

extern "C" void kernel_launch(void* const* d_in, const int* in_sizes, int n_in,
                              void* d_out, int out_size, void* d_ws, size_t ws_size,
                              hipStream_t stream) {
    const float* X  = (const float*)d_in[0];
    const float* Hp = (const float*)d_in[1];
    const float* Cp = (const float*)d_in[2];
    // input order: W_xf,b_xf, W_hf,b_hf, W_xi,b_xi, W_hi,b_hi, W_xc,b_xc, W_hc,b_hc, W_xo,b_xo, W_ho,b_ho
    WPtrs p;
    p.wx[0] = (const float*)d_in[3];  p.bx[0] = (const float*)d_in[4];
    p.wh[0] = (const float*)d_in[5];  p.bh[0] = (const float*)d_in[6];
    p.wx[1] = (const float*)d_in[7];  p.bx[1] = (const float*)d_in[8];
    p.wh[1] = (const float*)d_in[9];  p.bh[1] = (const float*)d_in[10];
    p.wx[2] = (const float*)d_in[11]; p.bx[2] = (const float*)d_in[12];
    p.wh[2] = (const float*)d_in[13]; p.bh[2] = (const float*)d_in[14];
    p.wx[3] = (const float*)d_in[15]; p.bx[3] = (const float*)d_in[16];
    p.wh[3] = (const float*)d_in[17]; p.bh[3] = (const float*)d_in[18];

    __bf16* wcat = (__bf16*)d_ws;
    float*  bsum = (float*)((char*)d_ws + 512 * 256 * 2);

    prep_weights<<<512, 256, 0, stream>>>(p, wcat, bsum);
    lstm_fused<<<B_ROWS / BM, 256, 0, stream>>>(X, Hp, Cp, wcat, bsum, (float*)d_out);
}